// Round 6
// baseline (37.573 us; speedup 1.0000x reference)
//
#include <hip/hip_runtime.h>
#include <hip/hip_bf16.h>

// Problem: B=8192, A=128, F=16, S=8
// x[b,a,:] = c[b,a,:] - q[b,a,:] * lam[b, seg[b,a]]
// lam[b,s] = (sum_{a: seg=s} c.q - charges[b,s]) / (sum_{a: seg=s} q.q)
//
// R6: R5 structure (wave-per-batch, no LDS/barrier/atomic, pair-atom mapping,
// full butterfly, normal stores) but TWO batches per wave with all loads
// issued up front -> 34 loads in flight per wave (2x MLP), batch1's loads
// overlap batch0's reduction chain. Grid = 1024 blocks.

#define B_ 8192
#define A_ 128
#define F_ 16
#define S_ 8

#define WPB 4                       // waves per block
#define VPB (A_ * F_ / 4)           // 512 float4 per batch

typedef float f4 __attribute__((ext_vector_type(4)));

__device__ __forceinline__ float dot4(const f4 a, const f4 b) {
    return a.x * b.x + a.y * b.y + a.z * b.z + a.w * b.w;
}

__device__ __forceinline__ void reduce_and_store(
    const f4* __restrict__ cv, const f4* __restrict__ qv,
    const int* __restrict__ sg, float charge, int lane,
    f4* __restrict__ op)
{
    float val[16];
#pragma unroll
    for (int k = 0; k < 16; ++k) val[k] = 0.0f;

#pragma unroll
    for (int t = 0; t < 4; ++t) {
        const float cq = dot4(cv[2 * t], qv[2 * t]) + dot4(cv[2 * t + 1], qv[2 * t + 1]);
        const float qq = dot4(qv[2 * t], qv[2 * t]) + dot4(qv[2 * t + 1], qv[2 * t + 1]);
        const int sj = sg[t];
#pragma unroll
        for (int s = 0; s < S_; ++s) {
            const bool m = (sj == s);
            val[s]     += m ? cq : 0.0f;
            val[8 + s] += m ? qq : 0.0f;
        }
    }

#pragma unroll
    for (int m = 1; m < 64; m <<= 1) {
#pragma unroll
        for (int k = 0; k < 16; ++k) val[k] += __shfl_xor(val[k], m, 64);
    }

    float qcsel = val[0], qqsel = val[8];
#pragma unroll
    for (int s = 1; s < S_; ++s) {
        const bool m = (lane == s);
        qcsel = m ? val[s]     : qcsel;
        qqsel = m ? val[8 + s] : qqsel;
    }
    const float lamv = (qcsel - charge) / qqsel;   // valid in lanes 0..7

#pragma unroll
    for (int t = 0; t < 4; ++t) {
        const float lam = __shfl(lamv, sg[t], 64);
        const int v0 = 2 * lane + 128 * t;
        f4 r0, r1;
        r0.x = cv[2 * t].x     - qv[2 * t].x     * lam;
        r0.y = cv[2 * t].y     - qv[2 * t].y     * lam;
        r0.z = cv[2 * t].z     - qv[2 * t].z     * lam;
        r0.w = cv[2 * t].w     - qv[2 * t].w     * lam;
        r1.x = cv[2 * t + 1].x - qv[2 * t + 1].x * lam;
        r1.y = cv[2 * t + 1].y - qv[2 * t + 1].y * lam;
        r1.z = cv[2 * t + 1].z - qv[2 * t + 1].z * lam;
        r1.w = cv[2 * t + 1].w - qv[2 * t + 1].w * lam;
        op[v0]     = r0;
        op[v0 + 1] = r1;
    }
}

__global__ __launch_bounds__(64 * WPB, 2) void qp_seg_norm_kernel(
    const float* __restrict__ c_iso,
    const float* __restrict__ int_iso,
    const int*   __restrict__ segment,
    const float* __restrict__ charges,
    float*       __restrict__ out)
{
    const int w    = threadIdx.x >> 6;
    const int lane = threadIdx.x & 63;
    const int b0   = blockIdx.x * WPB + w;       // 0..4095
    const int b1   = b0 + B_ / 2;                // 4096..8191

    float charge0 = 0.0f, charge1 = 0.0f;
    if (lane < S_) {
        charge0 = charges[(size_t)b0 * S_ + lane];
        charge1 = charges[(size_t)b1 * S_ + lane];
    }

    const f4* cp0 = reinterpret_cast<const f4*>(c_iso)   + (size_t)b0 * VPB;
    const f4* qp0 = reinterpret_cast<const f4*>(int_iso) + (size_t)b0 * VPB;
    const int* sp0 = segment + (size_t)b0 * A_;
    const f4* cp1 = reinterpret_cast<const f4*>(c_iso)   + (size_t)b1 * VPB;
    const f4* qp1 = reinterpret_cast<const f4*>(int_iso) + (size_t)b1 * VPB;
    const int* sp1 = segment + (size_t)b1 * A_;

    f4 cv0[8], qv0[8], cv1[8], qv1[8];
    int sg0[4], sg1[4];

    // Issue ALL loads for both batches up front (34 loads in flight).
#pragma unroll
    for (int t = 0; t < 4; ++t) {
        const int v0 = 2 * lane + 128 * t;
        cv0[2 * t]     = cp0[v0];
        cv0[2 * t + 1] = cp0[v0 + 1];
        qv0[2 * t]     = qp0[v0];
        qv0[2 * t + 1] = qp0[v0 + 1];
        sg0[t] = sp0[(lane >> 1) + 32 * t];
    }
#pragma unroll
    for (int t = 0; t < 4; ++t) {
        const int v0 = 2 * lane + 128 * t;
        cv1[2 * t]     = cp1[v0];
        cv1[2 * t + 1] = cp1[v0 + 1];
        qv1[2 * t]     = qp1[v0];
        qv1[2 * t + 1] = qp1[v0 + 1];
        sg1[t] = sp1[(lane >> 1) + 32 * t];
    }

    f4* op0 = reinterpret_cast<f4*>(out) + (size_t)b0 * VPB;
    f4* op1 = reinterpret_cast<f4*>(out) + (size_t)b1 * VPB;

    // Batch 0: reduce + store (frees cv0/qv0); batch 1 loads still landing.
    reduce_and_store(cv0, qv0, sg0, charge0, lane, op0);
    // Batch 1.
    reduce_and_store(cv1, qv1, sg1, charge1, lane, op1);
}

extern "C" void kernel_launch(void* const* d_in, const int* in_sizes, int n_in,
                              void* d_out, int out_size, void* d_ws, size_t ws_size,
                              hipStream_t stream) {
    const float* c_iso   = (const float*)d_in[0];
    const float* int_iso = (const float*)d_in[1];
    const int*   segment = (const int*)d_in[2];
    const float* charges = (const float*)d_in[3];
    float* out = (float*)d_out;

    qp_seg_norm_kernel<<<B_ / (2 * WPB), 64 * WPB, 0, stream>>>(
        c_iso, int_iso, segment, charges, out);
}

// Round 7
// 36.173 us; speedup vs baseline: 1.0387x; 1.0387x over previous
//
#include <hip/hip_runtime.h>
#include <hip/hip_bf16.h>

// Problem: B=8192, A=128, F=16, S=8
// x[b,a,:] = c[b,a,:] - q[b,a,:] * lam[b, seg[b,a]]
// lam[b,s] = (sum_{a: seg=s} c.q - charges[b,s]) / (sum_{a: seg=s} q.q)
//
// FINAL (= R5, best measured 36.07 us): wave-per-batch, no LDS/barrier/atomic,
// pair-atom lane mapping (4 (cq,qq,seg) triples/lane), full 6-step butterfly,
// shfl-broadcast lambda, normal stores.
// Measured: ~5.4 TB/s combined demand traffic = 86% of the 6.3 TB/s copy
// ceiling; VALUBusy ~9%; R4 (nt stores), R6 (2 batches/wave) both regressed.

#define B_ 8192
#define A_ 128
#define F_ 16
#define S_ 8

#define WPB 4                       // waves (=batches) per block
#define VPB (A_ * F_ / 4)           // 512 float4 per batch

typedef float f4 __attribute__((ext_vector_type(4)));

__device__ __forceinline__ float dot4(const f4 a, const f4 b) {
    return a.x * b.x + a.y * b.y + a.z * b.z + a.w * b.w;
}

__global__ __launch_bounds__(64 * WPB) void qp_seg_norm_kernel(
    const float* __restrict__ c_iso,
    const float* __restrict__ int_iso,
    const int*   __restrict__ segment,
    const float* __restrict__ charges,
    float*       __restrict__ out)
{
    const int w    = threadIdx.x >> 6;
    const int lane = threadIdx.x & 63;
    const int b    = blockIdx.x * WPB + w;

    float charge = 0.0f;
    if (lane < S_) charge = charges[(size_t)b * S_ + lane];

    const f4* cp = reinterpret_cast<const f4*>(c_iso)   + (size_t)b * VPB;
    const f4* qp = reinterpret_cast<const f4*>(int_iso) + (size_t)b * VPB;
    const int* sp = segment + (size_t)b * A_;

    f4 cv[8], qv[8];
    int sg[4];

#pragma unroll
    for (int t = 0; t < 4; ++t) {
        const int v0 = 2 * lane + 128 * t;     // float4 idx (pair v0, v0+1)
        cv[2 * t]     = cp[v0];
        cv[2 * t + 1] = cp[v0 + 1];
        qv[2 * t]     = qp[v0];
        qv[2 * t + 1] = qp[v0 + 1];
        sg[t] = sp[(lane >> 1) + 32 * t];      // atom = v0>>2
    }

    // Branchless per-segment accumulate: val[s]=qc, val[8+s]=qq. 4 triples.
    float val[16];
#pragma unroll
    for (int k = 0; k < 16; ++k) val[k] = 0.0f;

#pragma unroll
    for (int t = 0; t < 4; ++t) {
        const float cq = dot4(cv[2 * t], qv[2 * t]) + dot4(cv[2 * t + 1], qv[2 * t + 1]);
        const float qq = dot4(qv[2 * t], qv[2 * t]) + dot4(qv[2 * t + 1], qv[2 * t + 1]);
        const int sj = sg[t];
#pragma unroll
        for (int s = 0; s < S_; ++s) {
            const bool m = (sj == s);
            val[s]     += m ? cq : 0.0f;
            val[8 + s] += m ? qq : 0.0f;
        }
    }

    // Full butterfly all-reduce (16 values x 6 steps) -> all lanes have sums.
#pragma unroll
    for (int m = 1; m < 64; m <<= 1) {
#pragma unroll
        for (int k = 0; k < 16; ++k) val[k] += __shfl_xor(val[k], m, 64);
    }

    // lane s (s<8) computes lam[s].
    float qcsel = val[0], qqsel = val[8];
#pragma unroll
    for (int s = 1; s < S_; ++s) {
        const bool m = (lane == s);
        qcsel = m ? val[s]     : qcsel;
        qqsel = m ? val[8 + s] : qqsel;
    }
    const float lamv = (qcsel - charge) / qqsel;   // valid in lanes 0..7

    f4* op = reinterpret_cast<f4*>(out) + (size_t)b * VPB;
#pragma unroll
    for (int t = 0; t < 4; ++t) {
        const float lam = __shfl(lamv, sg[t], 64);
        const int v0 = 2 * lane + 128 * t;
        f4 r0, r1;
        r0.x = cv[2 * t].x     - qv[2 * t].x     * lam;
        r0.y = cv[2 * t].y     - qv[2 * t].y     * lam;
        r0.z = cv[2 * t].z     - qv[2 * t].z     * lam;
        r0.w = cv[2 * t].w     - qv[2 * t].w     * lam;
        r1.x = cv[2 * t + 1].x - qv[2 * t + 1].x * lam;
        r1.y = cv[2 * t + 1].y - qv[2 * t + 1].y * lam;
        r1.z = cv[2 * t + 1].z - qv[2 * t + 1].z * lam;
        r1.w = cv[2 * t + 1].w - qv[2 * t + 1].w * lam;
        op[v0]     = r0;
        op[v0 + 1] = r1;
    }
}

extern "C" void kernel_launch(void* const* d_in, const int* in_sizes, int n_in,
                              void* d_out, int out_size, void* d_ws, size_t ws_size,
                              hipStream_t stream) {
    const float* c_iso   = (const float*)d_in[0];
    const float* int_iso = (const float*)d_in[1];
    const int*   segment = (const int*)d_in[2];
    const float* charges = (const float*)d_in[3];
    float* out = (float*)d_out;

    qp_seg_norm_kernel<<<B_ / WPB, 64 * WPB, 0, stream>>>(
        c_iso, int_iso, segment, charges, out);
}